// Round 12
// baseline (2091.044 us; speedup 1.0000x reference)
//
#include <hip/hip_runtime.h>
#include <hip/hip_bf16.h>

#define CAP 64            // max stored in-degree (P(Poisson16 > 64) ~ 0)
#define KBUCK 391         // ceil(100000/256) dst-buckets
#define BSHIFT 8          // 256 nodes per bucket
#define BCAP 4608         // per-bucket edge capacity
#define CHUNK_A 8192      // edges per bucket chunk (write-amp: long runs, r6)
#define AITER (CHUNK_A / 256)
#define SA0 40            // GEMM B stride (80B row = 20-bank step: 2-way, free)
#define SFG 72            // consumer A stride (144B: 2-way, free)

typedef __attribute__((ext_vector_type(8))) short short8;
typedef __attribute__((ext_vector_type(4))) float f32x4;
typedef __hip_bfloat16 bf16;

__device__ inline unsigned short bfbits(float f) {
    bf16 b = __float2bfloat16(f);
    unsigned short u;
    __builtin_memcpy(&u, &b, 2);
    return u;
}

// ---- node 1: zero per-call state + weight prep (bf16 hi/lo transpose) ------
__global__ __launch_bounds__(256) void prep_kernel(
    const float* __restrict__ wr0, const float* __restrict__ wt0,
    const float* __restrict__ wr1, const float* __restrict__ wt1,
    const float* __restrict__ wr2, const float* __restrict__ wt2,
    bf16* __restrict__ hi, bf16* __restrict__ lo,
    int* __restrict__ gcur, float* __restrict__ gsum, int* __restrict__ gcnt,
    int* __restrict__ flags0, int* __restrict__ flags1, int* __restrict__ head_done,
    int ntiles)
{
    int gtid = blockIdx.x * 256 + threadIdx.x;
    int tot = gridDim.x * 256;
    for (int i = gtid; i < KBUCK; i += tot) gcur[i] = 0;
    for (int i = gtid; i < 64 * 64; i += tot) gsum[i] = 0.f;
    for (int i = gtid; i < 64; i += tot) gcnt[i] = 0;
    for (int i = gtid; i < ntiles; i += tot) { flags0[i] = 0; flags1[i] = 0; }
    if (gtid == 0) *head_done = 0;
    for (int idx = gtid; idx < 32768; idx += tot) {
        const float *wr, *wt;
        int n, k;
        if (idx < 16384)      { wr = wr0; wt = wt0; int q = idx;         n = q >> 7; k = q & 127; }
        else if (idx < 24576) { wr = wr1; wt = wt1; int q = idx - 16384; n = q >> 6; k = q & 63; }
        else                  { wr = wr2; wt = wt2; int q = idx - 24576; n = q >> 6; k = q & 63; }
        float w = (n < 64) ? wr[k * 64 + n] : wt[k * 64 + (n - 64)];
        bf16 h = __float2bfloat16(w);
        hi[idx] = h;
        lo[idx] = __float2bfloat16(w - __bfloat162float(h));
    }
}

// ---- bucket body: one 8192-edge chunk -> dst buckets (4B packed) -----------
__device__ inline void bucket_body(char* smem, int bb, const int* __restrict__ ei,
                                   int E, int* __restrict__ gcur,
                                   unsigned* __restrict__ bucketed)
{
    int* hist = (int*)smem;
    int* base = hist + KBUCK;
    const int e0 = bb * CHUNK_A;
    const int e1 = min(e0 + CHUNK_A, E);
    for (int i = threadIdx.x; i < KBUCK; i += 256) hist[i] = 0;
    __syncthreads();
    int dreg[AITER];
    #pragma unroll
    for (int it = 0; it < AITER; ++it) {
        int e = e0 + it * 256 + threadIdx.x;
        dreg[it] = (e < e1) ? ei[E + e] : -1;
        if (dreg[it] >= 0) atomicAdd(&hist[dreg[it] >> BSHIFT], 1);
    }
    __syncthreads();
    for (int i = threadIdx.x; i < KBUCK; i += 256) {
        int h = hist[i];
        base[i] = h ? atomicAdd(&gcur[i], h) : 0;
        hist[i] = 0;
    }
    __syncthreads();
    #pragma unroll
    for (int it = 0; it < AITER; ++it) {
        int e = e0 + it * 256 + threadIdx.x;
        if (e < e1) {
            int s = ei[e];
            int d = dreg[it];
            int b = d >> BSHIFT;
            int off = base[b] + atomicAdd(&hist[b], 1);
            if (off < BCAP)
                bucketed[(size_t)b * BCAP + off] = ((unsigned)s << 8) | (unsigned)(d & 255);
        }
    }
}

// ---- lin0 body: y(bf16)=x@w_rel ; r(bf16)=x@w_root+b (hi/lo weights) -------
__device__ inline void lin0_body(char* smem, int bx, const float* __restrict__ x,
    const bf16* __restrict__ whiT, const bf16* __restrict__ wloT,
    const float* __restrict__ b_rel, bf16* __restrict__ y, bf16* __restrict__ r, int N)
{
    bf16* As = (bf16*)smem;
    bf16* Bh = As + 128 * SA0;
    bf16* Bl = Bh + 128 * SA0;
    const int t = threadIdx.x;
    const int lane = t & 63;
    const int wid = t >> 6;
    const int wm = wid >> 1, wn = wid & 1;
    const int node0 = bx * 128;
    const int lrow = lane & 15;
    const int kgrp = lane >> 4;

    f32x4 acc[4][4];
    #pragma unroll
    for (int i = 0; i < 4; ++i)
        #pragma unroll
        for (int j = 0; j < 4; ++j) acc[i][j] = (f32x4){0.f, 0.f, 0.f, 0.f};

    for (int ks = 0; ks < 4; ++ks) {
        #pragma unroll
        for (int p = 0; p < 2; ++p) {
            int c = t + p * 256;
            int m = c >> 2, kc = c & 3;
            int row = node0 + m; if (row >= N) row = N - 1;
            const float* src = x + (size_t)row * 128 + ks * 32 + kc * 8;
            float4 v0 = *(const float4*)src;
            float4 v1 = *(const float4*)(src + 4);
            union { uint4 q; unsigned short s[8]; } pk;
            pk.s[0] = bfbits(v0.x); pk.s[1] = bfbits(v0.y);
            pk.s[2] = bfbits(v0.z); pk.s[3] = bfbits(v0.w);
            pk.s[4] = bfbits(v1.x); pk.s[5] = bfbits(v1.y);
            pk.s[6] = bfbits(v1.z); pk.s[7] = bfbits(v1.w);
            *(uint4*)&As[m * SA0 + kc * 8] = pk.q;
        }
        #pragma unroll
        for (int p = 0; p < 4; ++p) {
            int c = t + p * 256;
            int half = c >> 9;
            int cc = c & 511;
            int n = cc >> 2, kc = cc & 3;
            const bf16* w = half ? wloT : whiT;
            uint4 v = *(const uint4*)(w + (size_t)n * 128 + ks * 32 + kc * 8);
            if (half) *(uint4*)&Bl[n * SA0 + kc * 8] = v;
            else      *(uint4*)&Bh[n * SA0 + kc * 8] = v;
        }
        __syncthreads();

        short8 a[4], bh[4], bl[4];
        #pragma unroll
        for (int i = 0; i < 4; ++i)
            a[i] = *(const short8*)&As[(wm * 64 + i * 16 + lrow) * SA0 + kgrp * 8];
        #pragma unroll
        for (int j = 0; j < 4; ++j) {
            bh[j] = *(const short8*)&Bh[(wn * 64 + j * 16 + lrow) * SA0 + kgrp * 8];
            bl[j] = *(const short8*)&Bl[(wn * 64 + j * 16 + lrow) * SA0 + kgrp * 8];
        }
        #pragma unroll
        for (int i = 0; i < 4; ++i)
            #pragma unroll
            for (int j = 0; j < 4; ++j) {
                acc[i][j] = __builtin_amdgcn_mfma_f32_16x16x32_bf16(a[i], bh[j], acc[i][j], 0, 0, 0);
                acc[i][j] = __builtin_amdgcn_mfma_f32_16x16x32_bf16(a[i], bl[j], acc[i][j], 0, 0, 0);
            }
        __syncthreads();
    }

    #pragma unroll
    for (int i = 0; i < 4; ++i) {
        int mbase = node0 + wm * 64 + i * 16 + kgrp * 4;
        #pragma unroll
        for (int j = 0; j < 4; ++j) {
            int n = wn * 64 + j * 16 + lrow;
            #pragma unroll
            for (int v = 0; v < 4; ++v) {
                int m = mbase + v;
                if (m < N) {
                    float val = acc[i][j][v];
                    if (n < 64) y[(size_t)m * 64 + n] = __float2bfloat16(val);
                    else        r[(size_t)m * 64 + (n - 64)] = __float2bfloat16(val + b_rel[n - 64]);
                }
            }
        }
    }
}

// ---- node 2: 1:5-interleaved bucket | lin0 ---------------------------------
__global__ __launch_bounds__(256) void fused_l0_kernel(
    const float* __restrict__ x,
    const bf16* __restrict__ whiT, const bf16* __restrict__ wloT,
    const float* __restrict__ b_rel,
    bf16* __restrict__ y, bf16* __restrict__ r, int N,
    const int* __restrict__ ei, int E, int nbuckets, int nlin,
    int* __restrict__ gcur, unsigned* __restrict__ bucketed)
{
    extern __shared__ char smem[];
    int b = blockIdx.x;
    int q = b / 5, m = b % 5;
    if (m == 4) {
        if (q < nbuckets) bucket_body(smem, q, ei, E, gcur, bucketed);
    } else {
        int li = q * 4 + m;
        if (li < nlin) lin0_body(smem, li, x, whiT, wloT, b_rel, y, r, N);
    }
}

// ---- node 3: one block per bucket -> LDS counters, clustered slot writes ---
__global__ __launch_bounds__(256) void build_slots_kernel(
    const unsigned* __restrict__ bucketed, const int* __restrict__ gcur,
    int* __restrict__ cnt, int* __restrict__ slots, int N)
{
    __shared__ int lcnt[256];
    const int b = blockIdx.x;
    const int nb0 = b << BSHIFT;
    lcnt[threadIdx.x] = 0;
    __syncthreads();
    const int count = min(gcur[b], BCAP);
    const unsigned* src = bucketed + (size_t)b * BCAP;
    for (int i = threadIdx.x; i < count; i += 256) {
        unsigned p = src[i];
        int dl = (int)(p & 255u);
        int pos = atomicAdd(&lcnt[dl], 1);
        if (pos < CAP) slots[(size_t)(nb0 + dl) * CAP + pos] = (int)(p >> 8);
    }
    __syncthreads();
    int node = nb0 + threadIdx.x;
    if (node < N) cnt[node] = min(lcnt[threadIdx.x], CAP);
}

// ---- gather phase: h row for `node` -> pk (uint4) on nb==0 lanes -----------
__device__ inline bool gather_row(int node, const bf16* __restrict__ yin,
    const int* __restrict__ cnt, const int* __restrict__ slots,
    const bf16* __restrict__ rin, uint4* pk_out, float* f_out)
{
    const int sub = threadIdx.x & 31;
    const int nb = sub >> 3;
    const int ch = (sub & 7) * 8;
    const int deg = cnt[node];
    const int* sl = slots + (size_t)node * CAP;
    const unsigned short* yp = (const unsigned short*)yin;

    float a[8], b[8];
    #pragma unroll
    for (int k = 0; k < 8; ++k) { a[k] = 0.f; b[k] = 0.f; }

    #pragma unroll 2
    for (int j = nb; j < deg; j += 8) {
        int n0 = sl[j];
        uint4 v = *(const uint4*)(yp + (size_t)n0 * 64 + ch);
        a[0] += __uint_as_float(v.x << 16); a[1] += __uint_as_float(v.x & 0xffff0000u);
        a[2] += __uint_as_float(v.y << 16); a[3] += __uint_as_float(v.y & 0xffff0000u);
        a[4] += __uint_as_float(v.z << 16); a[5] += __uint_as_float(v.z & 0xffff0000u);
        a[6] += __uint_as_float(v.w << 16); a[7] += __uint_as_float(v.w & 0xffff0000u);
        int j2 = j + 4;
        if (j2 < deg) {
            int n1 = sl[j2];
            uint4 w = *(const uint4*)(yp + (size_t)n1 * 64 + ch);
            b[0] += __uint_as_float(w.x << 16); b[1] += __uint_as_float(w.x & 0xffff0000u);
            b[2] += __uint_as_float(w.y << 16); b[3] += __uint_as_float(w.y & 0xffff0000u);
            b[4] += __uint_as_float(w.z << 16); b[5] += __uint_as_float(w.z & 0xffff0000u);
            b[6] += __uint_as_float(w.w << 16); b[7] += __uint_as_float(w.w & 0xffff0000u);
        }
    }
    #pragma unroll
    for (int k = 0; k < 8; ++k) {
        a[k] += b[k];
        a[k] += __shfl_xor(a[k], 8);
        a[k] += __shfl_xor(a[k], 16);
    }
    if (nb == 0) {
        uint4 rv = *(const uint4*)((const unsigned short*)rin + (size_t)node * 64 + ch);
        float r0 = __uint_as_float(rv.x << 16), r1 = __uint_as_float(rv.x & 0xffff0000u);
        float r2 = __uint_as_float(rv.y << 16), r3 = __uint_as_float(rv.y & 0xffff0000u);
        float r4 = __uint_as_float(rv.z << 16), r5 = __uint_as_float(rv.z & 0xffff0000u);
        float r6 = __uint_as_float(rv.w << 16), r7 = __uint_as_float(rv.w & 0xffff0000u);
        f_out[0] = fmaxf(r0 + a[0], 0.f); f_out[1] = fmaxf(r1 + a[1], 0.f);
        f_out[2] = fmaxf(r2 + a[2], 0.f); f_out[3] = fmaxf(r3 + a[3], 0.f);
        f_out[4] = fmaxf(r4 + a[4], 0.f); f_out[5] = fmaxf(r5 + a[5], 0.f);
        f_out[6] = fmaxf(r6 + a[6], 0.f); f_out[7] = fmaxf(r7 + a[7], 0.f);
        union { uint4 q; unsigned short s[8]; } pk;
        #pragma unroll
        for (int k = 0; k < 8; ++k) pk.s[k] = bfbits(f_out[k]);
        *pk_out = pk.q;
        return true;
    }
    return false;
}

// ---- nodes 4,5: gather + last-arriver lin64 for the 128-row tile -----------
// Producers: agent (sc1) stores of h rows; flag fetch_add ACQ_REL; the 16th
// arriver stages the tile via agent loads and runs the MFMA lin.
__global__ __launch_bounds__(256) void gather_lin_kernel(
    const bf16* __restrict__ yin, const int* __restrict__ cnt,
    const int* __restrict__ slots, const bf16* __restrict__ rin,
    bf16* __restrict__ hmid,
    const bf16* __restrict__ whiT, const float* __restrict__ b_rel,
    bf16* __restrict__ yout, bf16* __restrict__ rout,
    int* __restrict__ tiles_done, int N)
{
    extern __shared__ char smem[];
    const int node = blockIdx.x * 8 + (threadIdx.x >> 5);
    const int ch = (threadIdx.x & 7) * 8;
    if (node < N) {
        uint4 pk; float f[8];
        if (gather_row(node, yin, cnt, slots, rin, &pk, f)) {
            unsigned long long* hp =
                (unsigned long long*)((unsigned short*)hmid + (size_t)node * 64 + ch);
            union { uint4 q; unsigned long long u[2]; } cv; cv.q = pk;
            __hip_atomic_store(hp,     cv.u[0], __ATOMIC_RELAXED, __HIP_MEMORY_SCOPE_AGENT);
            __hip_atomic_store(hp + 1, cv.u[1], __ATOMIC_RELAXED, __HIP_MEMORY_SCOPE_AGENT);
        }
    }
    __syncthreads();            // drains all vm stores (sc1 -> coherence point)
    __shared__ int amlast;
    const int tile = blockIdx.x >> 4;
    if (threadIdx.x == 0) {
        int expected = min(16, (int)gridDim.x - (tile << 4));
        int prev = __hip_atomic_fetch_add(&tiles_done[tile], 1,
                                          __ATOMIC_ACQ_REL, __HIP_MEMORY_SCOPE_AGENT);
        amlast = (prev == expected - 1);
    }
    __syncthreads();
    if (!amlast) return;

    // ---- consumer: lin64 for rows [tile*128, tile*128+128) ----
    bf16* As = (bf16*)smem;                  // [128][SFG]
    bf16* Bs = As + 128 * SFG;               // [128][SA0]
    const int t = threadIdx.x;
    const int node0 = tile * 128;
    for (int i = t; i < 2048; i += 256) {    // 128 rows x 16 8B-chunks
        int row = i >> 4;
        int c4 = (i & 15) * 4;
        int gr = node0 + row; if (gr >= N) gr = N - 1;
        unsigned long long v = __hip_atomic_load(
            (const unsigned long long*)((const unsigned short*)hmid + (size_t)gr * 64 + c4),
            __ATOMIC_RELAXED, __HIP_MEMORY_SCOPE_AGENT);
        *(unsigned long long*)&As[row * SFG + c4] = v;
    }
    const int lane = t & 63;
    const int wid = t >> 6;
    const int wm = wid >> 1, wn = wid & 1;
    const int lrow = lane & 15;
    const int kgrp = lane >> 4;
    f32x4 acc[4][4];
    #pragma unroll
    for (int i = 0; i < 4; ++i)
        #pragma unroll
        for (int j = 0; j < 4; ++j) acc[i][j] = (f32x4){0.f, 0.f, 0.f, 0.f};

    for (int ks = 0; ks < 2; ++ks) {
        #pragma unroll
        for (int p = 0; p < 2; ++p) {
            int c = t + p * 256;
            int n = c >> 2, kc = c & 3;
            *(uint4*)&Bs[n * SA0 + kc * 8] =
                *(const uint4*)(whiT + (size_t)n * 64 + ks * 32 + kc * 8);
        }
        __syncthreads();
        short8 a[4], b[4];
        #pragma unroll
        for (int i = 0; i < 4; ++i)
            a[i] = *(const short8*)&As[(wm * 64 + i * 16 + lrow) * SFG + ks * 32 + kgrp * 8];
        #pragma unroll
        for (int j = 0; j < 4; ++j)
            b[j] = *(const short8*)&Bs[(wn * 64 + j * 16 + lrow) * SA0 + kgrp * 8];
        #pragma unroll
        for (int i = 0; i < 4; ++i)
            #pragma unroll
            for (int j = 0; j < 4; ++j)
                acc[i][j] = __builtin_amdgcn_mfma_f32_16x16x32_bf16(a[i], b[j], acc[i][j], 0, 0, 0);
        __syncthreads();
    }

    #pragma unroll
    for (int i = 0; i < 4; ++i) {
        int mbase = node0 + wm * 64 + i * 16 + kgrp * 4;
        #pragma unroll
        for (int j = 0; j < 4; ++j) {
            int n = wn * 64 + j * 16 + lrow;
            #pragma unroll
            for (int v = 0; v < 4; ++v) {
                int m = mbase + v;
                if (m < N) {
                    float val = acc[i][j][v];
                    if (n < 64) yout[(size_t)m * 64 + n] = __float2bfloat16(val);
                    else        rout[(size_t)m * 64 + (n - 64)] = __float2bfloat16(val + b_rel[n - 64]);
                }
            }
        }
    }
}

// ---- node 6: gather2 + block-local pool + last-block head ------------------
__global__ __launch_bounds__(256) void gather_pool_head_kernel(
    const bf16* __restrict__ yin, const int* __restrict__ cnt,
    const int* __restrict__ slots, const bf16* __restrict__ rin,
    const int* __restrict__ batch, float* __restrict__ gsum,
    int* __restrict__ gcnt, int* __restrict__ head_done,
    const float* __restrict__ w1, const float* __restrict__ b1,
    const float* __restrict__ w2, const float* __restrict__ b2,
    float* __restrict__ out, int N)
{
    extern __shared__ char smem[];
    float* sm = (float*)smem;                 // [8][64] block h rows
    const int node0b = blockIdx.x * 8;
    const int node = node0b + (threadIdx.x >> 5);
    const int ch = (threadIdx.x & 7) * 8;
    if (node < N) {
        uint4 pk; float f[8];
        if (gather_row(node, yin, cnt, slots, rin, &pk, f)) {
            #pragma unroll
            for (int k = 0; k < 8; ++k)
                sm[(threadIdx.x >> 5) * 64 + ch + k] = f[k];
        }
    }
    __syncthreads();
    if (threadIdx.x < 64) {                   // wave 0 pools 8 contiguous rows
        int c = threadIdx.x;
        int nrows = min(8, N - node0b);
        if (nrows > 0) {
            int g = batch[node0b];
            float acc = 0.f; int run = 0;
            for (int i = 0; i < nrows; ++i) {
                int gg = batch[node0b + i];
                if (gg != g) {
                    atomicAdd(&gsum[g * 64 + c], acc);
                    if (c == 0) atomicAdd(&gcnt[g], run);
                    acc = 0.f; run = 0; g = gg;
                }
                acc += sm[i * 64 + c]; run++;
            }
            atomicAdd(&gsum[g * 64 + c], acc);
            if (c == 0) atomicAdd(&gcnt[g], run);
        }
    }
    __syncthreads();
    __shared__ int amlast;
    if (threadIdx.x == 0) {
        int prev = __hip_atomic_fetch_add(head_done, 1,
                                          __ATOMIC_ACQ_REL, __HIP_MEMORY_SCOPE_AGENT);
        amlast = (prev == (int)gridDim.x - 1);
    }
    __syncthreads();
    if (!amlast) return;

    // ---- head (bf16 pm/z in arena) ----
    bf16* pm = (bf16*)smem;                   // 64*64 bf16 = 8KB
    bf16* z  = pm + 64 * 64;                  // 8KB
    int t = threadIdx.x;
    for (int i = t; i < 64 * 64; i += 256) {
        int g = i >> 6;
        float sv = __hip_atomic_load(&gsum[i], __ATOMIC_RELAXED, __HIP_MEMORY_SCOPE_AGENT);
        int ci = __hip_atomic_load(&gcnt[g], __ATOMIC_RELAXED, __HIP_MEMORY_SCOPE_AGENT);
        float cf = ci < 1 ? 1.f : (float)ci;
        pm[i] = __float2bfloat16(sv / cf);
    }
    __syncthreads();
    for (int i = t; i < 64 * 64; i += 256) {
        int g = i >> 6, c = i & 63;
        float a = b1[c];
        #pragma unroll 8
        for (int k = 0; k < 64; ++k)
            a = fmaf(__bfloat162float(pm[g * 64 + k]), w1[k * 64 + c], a);
        z[i] = __float2bfloat16(fmaxf(a, 0.f));
    }
    __syncthreads();
    for (int i = t; i < 64 * 2; i += 256) {
        int g = i >> 1, o = i & 1;
        float a = b2[o];
        #pragma unroll 8
        for (int k = 0; k < 64; ++k)
            a = fmaf(__bfloat162float(z[g * 64 + k]), w2[k * 2 + o], a);
        out[i] = a;
    }
}

extern "C" void kernel_launch(void* const* d_in, const int* in_sizes, int n_in,
                              void* d_out, int out_size, void* d_ws, size_t ws_size,
                              hipStream_t stream)
{
    const float* x    = (const float*)d_in[0];
    const int*   ei   = (const int*)d_in[1];
    const int*   batch= (const int*)d_in[2];
    const float* wr0  = (const float*)d_in[3];
    const float* br0  = (const float*)d_in[4];
    const float* wt0  = (const float*)d_in[5];
    const float* wr1  = (const float*)d_in[6];
    const float* br1  = (const float*)d_in[7];
    const float* wt1  = (const float*)d_in[8];
    const float* wr2  = (const float*)d_in[9];
    const float* br2  = (const float*)d_in[10];
    const float* wt2  = (const float*)d_in[11];
    const float* hw1  = (const float*)d_in[12];
    const float* hb1  = (const float*)d_in[13];
    const float* hw2  = (const float*)d_in[14];
    const float* hb2  = (const float*)d_in[15];
    float* out = (float*)d_out;

    int N = in_sizes[0] / 128;   // 100000
    int E = in_sizes[1] / 2;     // 1600000

    size_t off = 0;
    auto alloc = [&](size_t bytes) -> void* {
        void* p = (char*)d_ws + off;
        off += (bytes + 255) & ~(size_t)255;
        return p;
    };
    int*      cnt      = (int*)alloc((size_t)N * 4);
    int*      slots    = (int*)alloc((size_t)N * CAP * 4);
    unsigned* bucketed = (unsigned*)alloc((size_t)KBUCK * BCAP * 4);
    int*      gcur     = (int*)alloc((size_t)KBUCK * 4);
    bf16* whiT = (bf16*)alloc(32768 * 2);
    bf16* wloT = (bf16*)alloc(32768 * 2);
    bf16* yA   = (bf16*)alloc((size_t)N * 64 * 2);
    bf16* rA   = (bf16*)alloc((size_t)N * 64 * 2);
    bf16* yB   = (bf16*)alloc((size_t)N * 64 * 2);
    bf16* rB   = (bf16*)alloc((size_t)N * 64 * 2);
    bf16* h0   = (bf16*)alloc((size_t)N * 64 * 2);
    bf16* h1   = (bf16*)alloc((size_t)N * 64 * 2);
    float* gsum = (float*)alloc((size_t)64 * 64 * 4);
    int*   gcnt = (int*)alloc((size_t)64 * 4);
    const int ntiles = (N + 127) / 128;                  // 782
    int* flags0 = (int*)alloc((size_t)ntiles * 4);
    int* flags1 = (int*)alloc((size_t)ntiles * 4);
    int* head_done = (int*)alloc(256);
    (void)ws_size; (void)n_in;

    const int gemm_blocks   = ntiles;                    // 782
    const int bucket_blocks = (E + CHUNK_A - 1) / CHUNK_A; // 196
    const int gather_blocks = (N + 7) / 8;               // 12500
    const int l0_grid = ((gemm_blocks + 3) / 4) * 5;     // 1:5 interleave cover
    const size_t LDS_L0 = (size_t)3 * 128 * SA0 * 2;     // 30720
    const size_t LDS_GL = (size_t)128 * SFG * 2 + (size_t)128 * SA0 * 2; // 28672
    const size_t LDS_PH = 16384;

    // 1: zero state + weight prep
    prep_kernel<<<128, 256, 0, stream>>>(wr0, wt0, wr1, wt1, wr2, wt2,
                                         whiT, wloT, gcur, gsum, gcnt,
                                         flags0, flags1, head_done, ntiles);
    // 2: interleaved bucket | lin0
    fused_l0_kernel<<<l0_grid, 256, LDS_L0, stream>>>(
        x, whiT, wloT, br0, yA, rA, N, ei, E, bucket_blocks, gemm_blocks,
        gcur, bucketed);
    // 3: build CSR slots
    build_slots_kernel<<<KBUCK, 256, 0, stream>>>(bucketed, gcur, cnt, slots, N);
    // 4: gather0 -> h0 (agent), last arriver runs lin1 -> yB,rB
    gather_lin_kernel<<<gather_blocks, 256, LDS_GL, stream>>>(
        yA, cnt, slots, rA, h0, whiT + 16384, br1, yB, rB, flags0, N);
    // 5: gather1 -> h1 (agent), last arriver runs lin2 -> yA,rA
    gather_lin_kernel<<<gather_blocks, 256, LDS_GL, stream>>>(
        yB, cnt, slots, rB, h1, whiT + 24576, br2, yA, rA, flags1, N);
    // 6: gather2 + block pool + last-block head
    gather_pool_head_kernel<<<gather_blocks, 256, LDS_PH, stream>>>(
        yA, cnt, slots, rA, batch, gsum, gcnt, head_done,
        hw1, hb1, hw2, hb2, out, N);
}